// Round 4
// baseline (226.381 us; speedup 1.0000x reference)
//
#include <hip/hip_runtime.h>

// SelfInteraction on MI355X.
// R3: 32x32x16 MFMA (2495 TF µbench), 1024-thr blocks (4 waves/SIMD), [z][v] stride-136
// LDS planes with b128 frag reads, fused cb (3 k per B-load), weights streamed once-ish.

#define C 128
#define NBATCH 8192

typedef _Float16 f16;
typedef _Float16 f16x8 __attribute__((ext_vector_type(8)));
typedef float f32x16 __attribute__((ext_vector_type(16)));

// ws layout:
// [0, 12MB)  : 3 f16 weight streams (ss, vv*inv_sqrt3, comb=Wsv+Wvs^T), each 2,097,152 f16
//              frag order [h2][vb4][u128][nt2][kt2][lane64][j8]
//                <-> W[u][vb*32+kt*16+(l>>5)*8+j][h*64+nt*32+(l&31)]
// [12MB,32MB): raw channel sums f32 [5][8192][128]  (ss, vv_scaled, cb0, cb1, cb2)
#define WSTREAM_F16_PER_C (2*4*128*2*2*64*8)   // 2,097,152 f16 = 4MB
#define NSTREAM 3
#define RAW_OFF_BYTES ((size_t)NSTREAM*WSTREAM_F16_PER_C*2)  // 12 MB
#define PSTR 136   // f16 stride per z-row: 272B = 16B-aligned, bank-shift 4/row

__device__ __forceinline__ f16x8 splat8(f16 v) { return (f16x8){v, v, v, v, v, v, v, v}; }
union U16x8 { uint4 u; f16x8 h; };
__device__ __forceinline__ f16x8 as_h8(uint4 v) { U16x8 x; x.u = v; return x.h; }
__device__ __forceinline__ f32x16 mfma32(f16x8 a, f16x8 b, f32x16 c) {
    return __builtin_amdgcn_mfma_f32_32x32x16_f16(a, b, c, 0, 0, 0);
}

// ---------------- weight prep ----------------
// grid 384: c = blockIdx>>7 (0=ss, 1=vv*inv_sqrt3, 2=Wsv+Wvs^T), u = blockIdx&127
__global__ __launch_bounds__(256) void prep_weights(
        const float* __restrict__ Wss, const float* __restrict__ Wvv,
        const float* __restrict__ Wsv, const float* __restrict__ Wvs,
        f16* __restrict__ out) {
    __shared__ float lds[128 * 130];
    int c = blockIdx.x >> 7;
    int u = blockIdx.x & 127;
    if (c == 2) {
        for (int i = threadIdx.x; i < 16384; i += 256) {
            int v = i >> 7, w = i & 127;
            lds[v * 130 + w] = Wsv[(size_t)u * 16384 + i] + Wvs[(size_t)v * 16384 + u * 128 + w];
        }
    } else {
        const float* src = (c == 0 ? Wss : Wvv) + (size_t)u * 16384;
        float sc = (c == 0) ? 1.0f : 0.57735026918962576f;
        for (int i = threadIdx.x; i < 16384; i += 256) {
            int v = i >> 7, w = i & 127;
            lds[v * 130 + w] = sc * src[i];
        }
    }
    __syncthreads();
    f16* dst = out + (size_t)c * WSTREAM_F16_PER_C;
    for (int pos = threadIdx.x; pos < 2048; pos += 256) {
        int hh = pos >> 10, vb = (pos >> 8) & 3, nt = (pos >> 7) & 1, kt = (pos >> 6) & 1;
        int l = pos & 63;
        int v0 = vb * 32 + kt * 16 + ((l >> 5) << 3);
        int w = hh * 64 + nt * 32 + (l & 31);
        f16x8 vals;
#pragma unroll
        for (int j = 0; j < 8; ++j) vals[j] = (f16)lds[(v0 + j) * 130 + w];
        size_t off = (((((size_t)(hh * 4 + vb) * 128 + u) * 2 + nt) * 2 + kt) * 64 + l) * 8;
        *(f16x8*)(dst + off) = vals;
    }
}

// 32x32 C/D tile write: row=(reg&3)+8*(reg>>2)+4*lk, col=l31
__device__ __forceinline__ void writeT32(float* __restrict__ raw, int c, int zb, int mtBase,
        int h, int ntOff, int l31, int lk, const f32x16& a, bool st) {
#pragma unroll
    for (int reg = 0; reg < 16; ++reg) {
        int row = (reg & 3) + 8 * (reg >> 2) + 4 * lk;
        int z = zb * 64 + mtBase + row;
        int ww = h * 64 + ntOff + l31;
        float* p = &raw[((size_t)c * NBATCH + z) * 128 + ww];
        if (st) *p = a[reg]; else *p += a[reg];
    }
}

// ---------------- main fused GEMM kernel ----------------
// grid 256: zb = bid>>1 (64-row z-tile), h = bid&1 (XCD-affine w-half). 1024 thr = 16 waves.
// Phase1: wave = (ch, nt, vb): ch 0=ss 1=vv; M=64 N=32 K-quarter(vb). 512 MFMA/wave.
// Phase2: wave = (mh, vb, nt): fused cb, 3 k per B-load; M=32 N=32 K-quarter. 768 MFMA/wave.
__global__ __launch_bounds__(1024, 4) void si_main(
        const float* __restrict__ x, const f16* __restrict__ wstream,
        float* __restrict__ raw) {
    __shared__ f16 xp[4][64 * PSTR];   // [plane][z][v], plane 0=x0, 1..3=x1k

    int zb = blockIdx.x >> 1;
    int h = blockIdx.x & 1;
    int tid = threadIdx.x;

    for (int i = tid; i < 64 * 512; i += 1024) {
        int z = i >> 9, col = i & 511;
        f16 fv = (f16)x[(size_t)(zb * 64 + z) * 512 + col];
        if (col < 128) {
            xp[0][z * PSTR + col] = fv;
        } else {
            int cc = col - 128;
            int v = cc / 3, k = cc - v * 3;
            xp[1 + k][z * PSTR + v] = fv;
        }
    }
    __syncthreads();

    int lane = tid & 63, w = tid >> 6;
    int l31 = lane & 31, lk = lane >> 5;

    // ================= phase 1: ss + vv =================
    int ch = w >> 3, nt1 = (w >> 2) & 1, vb1 = w & 3;
    f32x16 acc1[2] = {};
    {
        const uint4* bl = (const uint4*)(wstream + (size_t)ch * WSTREAM_F16_PER_C
                          + (size_t)h * (WSTREAM_F16_PER_C / 2))
                          + (size_t)vb1 * 32768 + nt1 * 128 + lane;
        uint4 b0[2], b1[2], bf[2];
#pragma unroll
        for (int kt = 0; kt < 2; ++kt) b0[kt] = bl[kt * 64];
#pragma unroll
        for (int kt = 0; kt < 2; ++kt) b1[kt] = bl[256 + kt * 64];

        if (ch == 0) {
            f16x8 vva[2][2];
#pragma unroll
            for (int mt = 0; mt < 2; ++mt)
#pragma unroll
                for (int kt = 0; kt < 2; ++kt)
                    vva[mt][kt] = *(const f16x8*)&xp[0][(mt * 32 + l31) * PSTR
                                                       + vb1 * 32 + kt * 16 + lk * 8];
#pragma unroll 4
            for (int uu = 0; uu < 128; ++uu) {
#pragma unroll
                for (int kt = 0; kt < 2; ++kt) bf[kt] = bl[(uu + 2) * 256 + kt * 64];
                f16 s0 = xp[0][l31 * PSTR + uu];
                f16 s1 = xp[0][(32 + l31) * PSTR + uu];
                f16x8 sp0 = splat8(s0), sp1 = splat8(s1);
                acc1[0] = mfma32(sp0 * vva[0][0], as_h8(b0[0]), acc1[0]);
                acc1[0] = mfma32(sp0 * vva[0][1], as_h8(b0[1]), acc1[0]);
                acc1[1] = mfma32(sp1 * vva[1][0], as_h8(b0[0]), acc1[1]);
                acc1[1] = mfma32(sp1 * vva[1][1], as_h8(b0[1]), acc1[1]);
#pragma unroll
                for (int kt = 0; kt < 2; ++kt) { b0[kt] = b1[kt]; b1[kt] = bf[kt]; }
            }
        } else {
            f16x8 vva[3][2][2];
#pragma unroll
            for (int p = 0; p < 3; ++p)
#pragma unroll
                for (int mt = 0; mt < 2; ++mt)
#pragma unroll
                    for (int kt = 0; kt < 2; ++kt)
                        vva[p][mt][kt] = *(const f16x8*)&xp[1 + p][(mt * 32 + l31) * PSTR
                                                                  + vb1 * 32 + kt * 16 + lk * 8];
#pragma unroll 2
            for (int uu = 0; uu < 128; ++uu) {
#pragma unroll
                for (int kt = 0; kt < 2; ++kt) bf[kt] = bl[(uu + 2) * 256 + kt * 64];
                f16x8 sp00 = splat8(xp[1][l31 * PSTR + uu]);
                f16x8 sp01 = splat8(xp[2][l31 * PSTR + uu]);
                f16x8 sp02 = splat8(xp[3][l31 * PSTR + uu]);
                f16x8 sp10 = splat8(xp[1][(32 + l31) * PSTR + uu]);
                f16x8 sp11 = splat8(xp[2][(32 + l31) * PSTR + uu]);
                f16x8 sp12 = splat8(xp[3][(32 + l31) * PSTR + uu]);
                f16x8 A00 = sp00 * vva[0][0][0] + sp01 * vva[1][0][0] + sp02 * vva[2][0][0];
                f16x8 A01 = sp00 * vva[0][0][1] + sp01 * vva[1][0][1] + sp02 * vva[2][0][1];
                f16x8 A10 = sp10 * vva[0][1][0] + sp11 * vva[1][1][0] + sp12 * vva[2][1][0];
                f16x8 A11 = sp10 * vva[0][1][1] + sp11 * vva[1][1][1] + sp12 * vva[2][1][1];
                acc1[0] = mfma32(A00, as_h8(b0[0]), acc1[0]);
                acc1[0] = mfma32(A01, as_h8(b0[1]), acc1[0]);
                acc1[1] = mfma32(A10, as_h8(b0[0]), acc1[1]);
                acc1[1] = mfma32(A11, as_h8(b0[1]), acc1[1]);
#pragma unroll
                for (int kt = 0; kt < 2; ++kt) { b0[kt] = b1[kt]; b1[kt] = bf[kt]; }
            }
        }
    }
    // phase1 reduce: 4 rounds; wave vb1==r writes its (ch, nt) tile
#pragma unroll
    for (int r = 0; r < 4; ++r) {
        __threadfence_block();
        __syncthreads();
        if (vb1 == r) {
            writeT32(raw, ch, zb, 0,  h, nt1 * 32, l31, lk, acc1[0], r == 0);
            writeT32(raw, ch, zb, 32, h, nt1 * 32, l31, lk, acc1[1], r == 0);
        }
    }

    // ================= phase 2: fused cb (3 k per B-load) =================
    int mh = w >> 3, vb2 = (w >> 1) & 3, nt2 = w & 1;
    f32x16 acc2[3] = {};
    {
        f16x8 vvb[3][2];
#pragma unroll
        for (int p = 0; p < 3; ++p)
#pragma unroll
            for (int kt = 0; kt < 2; ++kt)
                vvb[p][kt] = *(const f16x8*)&xp[1 + p][(mh * 32 + l31) * PSTR
                                                      + vb2 * 32 + kt * 16 + lk * 8];
        const uint4* bl = (const uint4*)(wstream + (size_t)2 * WSTREAM_F16_PER_C
                          + (size_t)h * (WSTREAM_F16_PER_C / 2))
                          + (size_t)vb2 * 32768 + nt2 * 128 + lane;
        uint4 b0[2], b1[2], bf[2];
#pragma unroll
        for (int kt = 0; kt < 2; ++kt) b0[kt] = bl[kt * 64];
#pragma unroll
        for (int kt = 0; kt < 2; ++kt) b1[kt] = bl[256 + kt * 64];
#pragma unroll 2
        for (int uu = 0; uu < 128; ++uu) {
#pragma unroll
            for (int kt = 0; kt < 2; ++kt) bf[kt] = bl[(uu + 2) * 256 + kt * 64];
            f16x8 sp = splat8(xp[0][(mh * 32 + l31) * PSTR + uu]);
            acc2[0] = mfma32(sp * vvb[0][0], as_h8(b0[0]), acc2[0]);
            acc2[0] = mfma32(sp * vvb[0][1], as_h8(b0[1]), acc2[0]);
            acc2[1] = mfma32(sp * vvb[1][0], as_h8(b0[0]), acc2[1]);
            acc2[1] = mfma32(sp * vvb[1][1], as_h8(b0[1]), acc2[1]);
            acc2[2] = mfma32(sp * vvb[2][0], as_h8(b0[0]), acc2[2]);
            acc2[2] = mfma32(sp * vvb[2][1], as_h8(b0[1]), acc2[2]);
#pragma unroll
            for (int kt = 0; kt < 2; ++kt) { b0[kt] = b1[kt]; b1[kt] = bf[kt]; }
        }
    }
    // phase2 reduce: 4 rounds; wave writes tile k=(vb2-r)&3 (k<3) at (mh, nt2)
#pragma unroll
    for (int r = 0; r < 4; ++r) {
        __threadfence_block();
        __syncthreads();
        int k = (vb2 - r) & 3;
        if (k == 0)      writeT32(raw, 2, zb, mh * 32, h, nt2 * 32, l31, lk, acc2[0], r == 0);
        else if (k == 1) writeT32(raw, 3, zb, mh * 32, h, nt2 * 32, l31, lk, acc2[1], r == 0);
        else if (k == 2) writeT32(raw, 4, zb, mh * 32, h, nt2 * 32, l31, lk, acc2[2], r == 0);
    }
}

// ---------------- finalize ----------------
__global__ __launch_bounds__(64) void si_finalize(const float* __restrict__ raw,
                                                  float* __restrict__ out) {
    const float PW0 = 0.0055242717280199f;   // 1/sqrt(2*128*128) == pw1/sqrt(3)
    int z = blockIdx.x;
    int t = threadIdx.x;
    const size_t CS = (size_t)NBATCH * 128;
    const float* r0 = raw + (size_t)z * 128;

    float y0A = PW0 * (r0[t] + r0[CS + t]);
    float y0B = PW0 * (r0[t + 64] + r0[CS + t + 64]);
    float s1 = y0A + y0B, s2 = y0A * y0A + y0B * y0B;
    for (int o = 32; o; o >>= 1) {
        s1 += __shfl_xor(s1, o);
        s2 += __shfl_xor(s2, o);
    }
    float mean = s1 * (1.0f / 128.0f);
    float var = (s2 - 128.0f * mean * mean) * (1.0f / 127.0f);
    float sc = 1.0f / (sqrtf(fmaxf(var, 0.0f)) + 1e-9f);
    out[(size_t)z * 512 + t] = y0A * sc;
    out[(size_t)z * 512 + t + 64] = y0B * sc;

    float yA[3], yB[3];
    float nA = 1e-9f, nB = 1e-9f;
#pragma unroll
    for (int k = 0; k < 3; ++k) {
        yA[k] = PW0 * r0[CS * (2 + k) + t];
        yB[k] = PW0 * r0[CS * (2 + k) + t + 64];
        nA += yA[k] * yA[k];
        nB += yB[k] * yB[k];
    }
    nA = sqrtf(nA);
    nB = sqrtf(nB);
    float t1 = nA + nB, t2 = nA * nA + nB * nB;
    for (int o = 32; o; o >>= 1) {
        t1 += __shfl_xor(t1, o);
        t2 += __shfl_xor(t2, o);
    }
    float meanv = t1 * (1.0f / 128.0f);
    float varv = (t2 - 128.0f * meanv * meanv) * (1.0f / 127.0f);
    float sv = 1.0f / (sqrtf(fmaxf(varv, 0.0f)) + 1e-9f);
#pragma unroll
    for (int k = 0; k < 3; ++k) {
        out[(size_t)z * 512 + 128 + t * 3 + k] = yA[k] * sv;
        out[(size_t)z * 512 + 128 + (t + 64) * 3 + k] = yB[k] * sv;
    }
}

extern "C" void kernel_launch(void* const* d_in, const int* in_sizes, int n_in,
                              void* d_out, int out_size, void* d_ws, size_t ws_size,
                              hipStream_t stream) {
    const float* x = (const float*)d_in[0];
    const float* Wss = (const float*)d_in[1];
    const float* Wvv = (const float*)d_in[2];
    const float* Wsv = (const float*)d_in[3];
    const float* Wvs = (const float*)d_in[4];
    f16* wstream = (f16*)d_ws;
    float* raw = (float*)((char*)d_ws + RAW_OFF_BYTES);
    float* out = (float*)d_out;

    hipLaunchKernelGGL(prep_weights, dim3(384), dim3(256), 0, stream,
                       Wss, Wvv, Wsv, Wvs, wstream);
    hipLaunchKernelGGL(si_main, dim3(256), dim3(1024), 0, stream, x, wstream, raw);
    hipLaunchKernelGGL(si_finalize, dim3(NBATCH), dim3(64), 0, stream, raw, out);
}